// Round 6
// baseline (446.819 us; speedup 1.0000x reference)
//
#include <hip/hip_runtime.h>

// may_alias types for all LDS/global reinterpret accesses
typedef __bf16 bf16v8 __attribute__((ext_vector_type(8)));
typedef bf16v8 bf16x8 __attribute__((may_alias));
typedef unsigned int u32v2 __attribute__((ext_vector_type(2)));
typedef u32v2 u32x2 __attribute__((may_alias));
typedef unsigned short u16v;
typedef u16v u16 __attribute__((may_alias));
typedef float f32x4 __attribute__((ext_vector_type(4)));
typedef unsigned int u32;

#define MEMFENCE() asm volatile("" ::: "memory")

union B8 { u32 u[4]; bf16v8 v; };

__device__ __forceinline__ u32 cvtpk(float lo, float hi) {
    u32 r;
    asm("v_cvt_pk_bf16_f32 %0, %1, %2" : "=v"(r) : "v"(lo), "v"(hi));
    return r;
}

__device__ __forceinline__ unsigned short f2b(float f) {
    union { float f; unsigned u; } a; a.f = f;
    unsigned r = a.u + 0x7FFFu + ((a.u >> 16) & 1u);   // RNE
    return (unsigned short)(r >> 16);
}

// ---- weight prep (R1-verbatim) ----
__global__ void prep_weights(const float* __restrict__ Wq,
                             const float* __restrict__ Wkv,
                             const float* __restrict__ Wp,
                             const float* __restrict__ bq,
                             const float* __restrict__ bkv,
                             u16* __restrict__ wt,
                             u16* __restrict__ wpt,
                             float* __restrict__ b_all)
{
    int idx = blockIdx.x * 256 + threadIdx.x;
    if (idx < 196608) {                       // 768*256
        int c = idx >> 8, k = idx & 255;
        float v = (c < 256) ? Wq[k * 256 + c] : Wkv[k * 512 + (c - 256)];
        wt[idx] = f2b(v);
    } else if (idx < 262144) {                // + 256*256
        int j = idx - 196608;
        int c = j >> 8, k = j & 255;
        wpt[j] = f2b(Wp[k * 256 + c]);
    } else if (idx < 262912) {                // + 768 biases
        int i = idx - 262144;
        b_all[i] = (i < 256) ? bq[i] : bkv[i - 256];
    }
}

// Deltas from validated R5: no XCD remap (b=bid); QKV A-frags direct from global x
// (cvtpk, value-identical); no xs staging phase; 2 barriers instead of 4; bk hoisted;
// V^T lives in region-Y chunk; P lives in region X (later O_lds overlay).
// LDS map (64 KiB): region X [0,32768): per-wave P tile 8KB at w*8192 -> O_lds[64][256]
//                   region Y [32768,65536): per-wave chunk 8KB: Q -> K -> V^T
// Swizzle everywhere: byte ^= (row&7)<<4.
__global__ __launch_bounds__(256, 2)
void fused_win_attn(const float* __restrict__ x,
                    const float* __restrict__ mask,
                    const u16* __restrict__ wt,
                    const u16* __restrict__ wpt,
                    const float* __restrict__ b_all,
                    const float* __restrict__ bp,
                    float* __restrict__ out)
{
    __shared__ __align__(16) unsigned char smem[65536];
    const int b   = blockIdx.x;
    const int wdw = b & 255;                    // window index (batch-major layout)

    const int tid = threadIdx.x;
    const int w   = tid >> 6;
    const int l   = tid & 63;
    const int lr  = l & 15;
    const int lg  = l >> 4;
    const int chunkoff = 32768 + w * 8192;      // region Y: Q -> K -> V^T
    const int poff     = w * 8192;              // region X: P (later O_lds overlay)
    const int wcol     = w * 64;
    const float scale = 0.17677669529663687f;   // 1/sqrt(32)

    f32x4 zero = {0.f, 0.f, 0.f, 0.f};

    // ---------- Phase 1: single-pass QKV, A-frags direct from global ----------
    const float* xb = x + (size_t)b * 16384;
    u32 pkK[2][2][4][2], pkV[2][2][4][2];   // [hf][t][tj][epair]
#pragma unroll
    for (int hf = 0; hf < 2; ++hf) {
        f32x4 qa[2][4], ka[2][4], va[2][4];
#pragma unroll
        for (int t = 0; t < 2; ++t)
#pragma unroll
            for (int tj = 0; tj < 4; ++tj) { qa[t][tj] = zero; ka[t][tj] = zero; va[t][tj] = zero; }
#pragma unroll
        for (int ks = 0; ks < 8; ++ks) {
            bf16v8 af[2];
#pragma unroll
            for (int t = 0; t < 2; ++t) {
                const float* xp = xb + (hf * 32 + t * 16 + lr) * 256 + ks * 32 + lg * 8;
                float4 f0 = *(const float4*)xp;
                float4 f1 = *(const float4*)(xp + 4);
                B8 tmp;
                tmp.u[0] = cvtpk(f0.x, f0.y); tmp.u[1] = cvtpk(f0.z, f0.w);
                tmp.u[2] = cvtpk(f1.x, f1.y); tmp.u[3] = cvtpk(f1.z, f1.w);
                af[t] = tmp.v;
            }
#pragma unroll
            for (int tj = 0; tj < 4; ++tj) {
                const u16* wp0 = wt + (size_t)(wcol + tj * 16 + lr) * 256 + ks * 32 + lg * 8;
                bf16v8 bwq = *(const bf16x8*)(wp0);
                bf16v8 bwk = *(const bf16x8*)(wp0 + 256 * 256);
                bf16v8 bwv = *(const bf16x8*)(wp0 + 512 * 256);
#pragma unroll
                for (int t = 0; t < 2; ++t) {
                    qa[t][tj] = __builtin_amdgcn_mfma_f32_16x16x32_bf16(af[t], bwq, qa[t][tj], 0, 0, 0);
                    ka[t][tj] = __builtin_amdgcn_mfma_f32_16x16x32_bf16(af[t], bwk, ka[t][tj], 0, 0, 0);
                    va[t][tj] = __builtin_amdgcn_mfma_f32_16x16x32_bf16(af[t], bwv, va[t][tj], 0, 0, 0);
                }
            }
        }
        // stage Q half (R5 formula); park K,V (+bias) packed
#pragma unroll
        for (int tj = 0; tj < 4; ++tj) {
            float bqv = b_all[wcol + tj * 16 + lr];
            float bkr = b_all[256 + wcol + tj * 16 + lr];
            float bvr = b_all[512 + wcol + tj * 16 + lr];
            int col2 = (tj * 16 + lr) * 2;
#pragma unroll
            for (int t = 0; t < 2; ++t) {
#pragma unroll
                for (int e = 0; e < 4; ++e) {
                    int tok = hf * 32 + t * 16 + lg * 4 + e;
                    *(u16*)(smem + chunkoff + tok * 128 + (col2 ^ ((tok & 7) << 4)))
                        = f2b(qa[t][tj][e] + bqv);
                }
                pkK[hf][t][tj][0] = cvtpk(ka[t][tj][0] + bkr, ka[t][tj][1] + bkr);
                pkK[hf][t][tj][1] = cvtpk(ka[t][tj][2] + bkr, ka[t][tj][3] + bkr);
                pkV[hf][t][tj][0] = cvtpk(va[t][tj][0] + bvr, va[t][tj][1] + bvr);
                pkV[hf][t][tj][1] = cvtpk(va[t][tj][2] + bvr, va[t][tj][3] + bvr);
            }
        }
    }

    MEMFENCE();
    // read Q A-frags (R5 formula)
    bf16v8 aq[2][4];
#pragma unroll
    for (int hl = 0; hl < 2; ++hl)
#pragma unroll
        for (int ti = 0; ti < 4; ++ti) {
            int row = ti * 16 + lr;
            aq[hl][ti] = *(const bf16x8*)(smem + chunkoff + row * 128 +
                                          ((hl * 64 + lg * 16) ^ ((row & 7) << 4)));
        }
    MEMFENCE();

    // stage K into chunk (overwrite Q; R5 formula)
#pragma unroll
    for (int hf = 0; hf < 2; ++hf)
#pragma unroll
        for (int t = 0; t < 2; ++t)
#pragma unroll
            for (int tj = 0; tj < 4; ++tj) {
                int col2 = (tj * 16 + lr) * 2;
#pragma unroll
                for (int ep = 0; ep < 2; ++ep) {
                    u32 u = pkK[hf][t][tj][ep];
                    int tok0 = hf * 32 + t * 16 + lg * 4 + ep * 2;
                    *(u16*)(smem + chunkoff + tok0 * 128 + (col2 ^ ((tok0 & 7) << 4))) = (unsigned short)u;
                    *(u16*)(smem + chunkoff + (tok0 + 1) * 128 + (col2 ^ (((tok0 + 1) & 7) << 4))) = (unsigned short)(u >> 16);
                }
            }
    MEMFENCE();

    // hoist K B-frags for BOTH heads (R5 phase-3 bk formula, read before V^T overwrites)
    bf16v8 bkF[2][4];
#pragma unroll
    for (int hl = 0; hl < 2; ++hl)
#pragma unroll
        for (int tj = 0; tj < 4; ++tj) {
            int n = tj * 16 + lr;
            bkF[hl][tj] = *(const bf16x8*)(smem + chunkoff + n * 128 +
                                           ((hl * 64 + lg * 16) ^ ((n & 7) << 4)));
        }
    MEMFENCE();

    // stage V^T into chunk (overwrite K; R5 formula, base = chunkoff)
#pragma unroll
    for (int hf = 0; hf < 2; ++hf)
#pragma unroll
        for (int t = 0; t < 2; ++t)
#pragma unroll
            for (int tj = 0; tj < 4; ++tj) {
                int c = tj * 16 + lr;
                int tok0 = hf * 32 + t * 16 + lg * 4;
                u32x2 pv2; pv2[0] = pkV[hf][t][tj][0]; pv2[1] = pkV[hf][t][tj][1];
                *(u32x2*)(smem + chunkoff + c * 128 + ((tok0 * 2) ^ ((c & 7) << 4))) = pv2;
            }
    MEMFENCE();

    // ---------- Phase 2: attention per head (no barriers; all per-wave private) ----------
    f32x4 oH[2][4][2];
    const float* mbase = mask + (size_t)wdw * 4096;
#pragma unroll
    for (int hl = 0; hl < 2; ++hl) {
        // S = Q K^T (R5 formulas)
        f32x4 sH[4][4];
#pragma unroll
        for (int ti = 0; ti < 4; ++ti)
#pragma unroll
            for (int tj = 0; tj < 4; ++tj)
                sH[ti][tj] = __builtin_amdgcn_mfma_f32_16x16x32_bf16(aq[hl][ti], bkF[hl][tj], zero, 0, 0, 0);

        // scale + mask add (global mask, R5-verbatim)
#pragma unroll
        for (int ti = 0; ti < 4; ++ti)
#pragma unroll
            for (int e = 0; e < 4; ++e) {
                int row = ti * 16 + lg * 4 + e;
#pragma unroll
                for (int tj = 0; tj < 4; ++tj)
                    sH[ti][tj][e] = sH[ti][tj][e] * scale + mbase[row * 64 + tj * 16 + lr];
            }
        // softmax (R5-verbatim shfl reduction)
        float inv[4][4];
#pragma unroll
        for (int ti = 0; ti < 4; ++ti)
#pragma unroll
            for (int e = 0; e < 4; ++e) {
                float v0 = sH[ti][0][e], v1 = sH[ti][1][e];
                float v2 = sH[ti][2][e], v3 = sH[ti][3][e];
                float m = fmaxf(fmaxf(v0, v1), fmaxf(v2, v3));
#pragma unroll
                for (int d = 1; d < 16; d <<= 1) m = fmaxf(m, __shfl_xor(m, d));
                v0 = __expf(v0 - m); v1 = __expf(v1 - m);
                v2 = __expf(v2 - m); v3 = __expf(v3 - m);
                float s = v0 + v1 + v2 + v3;
#pragma unroll
                for (int d = 1; d < 16; d <<= 1) s += __shfl_xor(s, d);
                inv[ti][e] = 1.0f / s;
                sH[ti][0][e] = v0; sH[ti][1][e] = v1;
                sH[ti][2][e] = v2; sH[ti][3][e] = v3;
            }
        // write unnormalized P into region-X tile (R5 formula, base = poff)
#pragma unroll
        for (int ti = 0; ti < 4; ++ti)
#pragma unroll
            for (int e = 0; e < 4; ++e) {
                int row = ti * 16 + lg * 4 + e;
#pragma unroll
                for (int tj = 0; tj < 4; ++tj)
                    *(u16*)(smem + poff + row * 128 + ((((tj * 16 + lr) * 2)) ^ ((row & 7) << 4)))
                        = f2b(sH[ti][tj][e]);
            }
        MEMFENCE();
        // PV (R5 formulas; ap from poff, bv from chunkoff)
#pragma unroll
        for (int ti = 0; ti < 4; ++ti)
#pragma unroll
            for (int tj = 0; tj < 2; ++tj) oH[hl][ti][tj] = zero;
#pragma unroll
        for (int kb = 0; kb < 2; ++kb) {
            bf16v8 ap[4], bv[2];
#pragma unroll
            for (int ti = 0; ti < 4; ++ti) {
                int row = ti * 16 + lr;
                ap[ti] = *(const bf16x8*)(smem + poff + row * 128 +
                                          ((kb * 64 + lg * 16) ^ ((row & 7) << 4)));
            }
#pragma unroll
            for (int tj = 0; tj < 2; ++tj) {
                int c = hl * 32 + tj * 16 + lr;
                bv[tj] = *(const bf16x8*)(smem + chunkoff + c * 128 +
                                          ((kb * 64 + lg * 16) ^ ((c & 7) << 4)));
            }
#pragma unroll
            for (int ti = 0; ti < 4; ++ti)
#pragma unroll
                for (int tj = 0; tj < 2; ++tj)
                    oH[hl][ti][tj] = __builtin_amdgcn_mfma_f32_16x16x32_bf16(ap[ti], bv[tj], oH[hl][ti][tj], 0, 0, 0);
        }
        MEMFENCE();
        // normalize O rows
#pragma unroll
        for (int ti = 0; ti < 4; ++ti)
#pragma unroll
            for (int tj = 0; tj < 2; ++tj)
#pragma unroll
                for (int e = 0; e < 4; ++e)
                    oH[hl][ti][tj][e] *= inv[ti][e];
    }

    __syncthreads();   // #1: all waves done with P tiles -> region X becomes O_lds

    // ---------- Phase 3 (R5-verbatim): stage O -> O_lds[64][256] at base 0 ----------
#pragma unroll
    for (int hl = 0; hl < 2; ++hl)
#pragma unroll
        for (int ti = 0; ti < 4; ++ti)
#pragma unroll
            for (int tj = 0; tj < 2; ++tj)
#pragma unroll
                for (int e = 0; e < 4; ++e) {
                    int row = ti * 16 + lg * 4 + e;
                    int cg  = (2 * w + hl) * 32 + tj * 16 + lr;
                    *(u16*)(smem + row * 512 + ((cg * 2) ^ ((row & 7) << 4)))
                        = f2b(oH[hl][ti][tj][e]);
                }
    __syncthreads();   // #2

    // ---------- Phase 4 (R5-verbatim): output projection ----------
    f32x4 pacc[4][4];
#pragma unroll
    for (int ti = 0; ti < 4; ++ti)
#pragma unroll
        for (int tj = 0; tj < 4; ++tj) pacc[ti][tj] = zero;
#pragma unroll
    for (int ks = 0; ks < 8; ++ks) {
        bf16v8 a_[4];
#pragma unroll
        for (int ti = 0; ti < 4; ++ti) {
            int row = ti * 16 + lr;
            a_[ti] = *(const bf16x8*)(smem + row * 512 + ((ks * 64 + lg * 16) ^ ((row & 7) << 4)));
        }
#pragma unroll
        for (int tj = 0; tj < 4; ++tj) {
            bf16v8 bw = *(const bf16x8*)(wpt + (size_t)(wcol + tj * 16 + lr) * 256 + ks * 32 + lg * 8);
#pragma unroll
            for (int ti = 0; ti < 4; ++ti)
                pacc[ti][tj] = __builtin_amdgcn_mfma_f32_16x16x32_bf16(a_[ti], bw, pacc[ti][tj], 0, 0, 0);
        }
    }
    // epilogue: + bp, store fp32, tj-inner (256B contiguous spans per (ti,e))
    float* ob = out + (size_t)b * 16384;
    float bpr[4];
#pragma unroll
    for (int tj = 0; tj < 4; ++tj) bpr[tj] = bp[wcol + tj * 16 + lr];
#pragma unroll
    for (int ti = 0; ti < 4; ++ti)
#pragma unroll
        for (int e = 0; e < 4; ++e) {
            int row = ti * 16 + lg * 4 + e;
            float* orow = ob + row * 256 + wcol;
#pragma unroll
            for (int tj = 0; tj < 4; ++tj)
                orow[tj * 16 + lr] = pacc[ti][tj][e] + bpr[tj];
        }
}

extern "C" void kernel_launch(void* const* d_in, const int* in_sizes, int n_in,
                              void* d_out, int out_size, void* d_ws, size_t ws_size,
                              hipStream_t stream) {
    const float* x    = (const float*)d_in[0];
    const float* mask = (const float*)d_in[1];
    const float* Wq   = (const float*)d_in[2];
    const float* bq   = (const float*)d_in[3];
    const float* Wkv  = (const float*)d_in[4];
    const float* bkv  = (const float*)d_in[5];
    const float* Wp   = (const float*)d_in[6];
    const float* bp   = (const float*)d_in[7];
    float* out = (float*)d_out;

    u16*   wt    = (u16*)d_ws;                 // 768*256 bf16
    u16*   wpt   = wt + 768 * 256;             // 256*256 bf16
    float* b_all = (float*)(wpt + 256 * 256);  // 768 f32

    prep_weights<<<1027, 256, 0, stream>>>(Wq, Wkv, Wp, bq, bkv, wt, wpt, b_all);
    fused_win_attn<<<2048, 256, 0, stream>>>(x, mask, wt, wpt, b_all, bp, out);
}

// Round 7
// 297.502 us; speedup vs baseline: 1.5019x; 1.5019x over previous
//
#include <hip/hip_runtime.h>

// may_alias types for all LDS/global reinterpret accesses
typedef __bf16 bf16v8 __attribute__((ext_vector_type(8)));
typedef bf16v8 bf16x8 __attribute__((may_alias));
typedef unsigned int u32v2 __attribute__((ext_vector_type(2)));
typedef u32v2 u32x2 __attribute__((may_alias));
typedef unsigned short u16v8 __attribute__((ext_vector_type(8)));
typedef u16v8 u16x8 __attribute__((may_alias));
typedef unsigned short u16v;
typedef u16v u16 __attribute__((may_alias));
typedef float f32x4 __attribute__((ext_vector_type(4)));
typedef unsigned int u32;

#define MEMFENCE() asm volatile("" ::: "memory")

union B8 { u32 u[4]; bf16v8 v; };

__device__ __forceinline__ u32 cvtpk(float lo, float hi) {
    u32 r;
    asm("v_cvt_pk_bf16_f32 %0, %1, %2" : "=v"(r) : "v"(lo), "v"(hi));
    return r;
}

__device__ __forceinline__ unsigned short f2b(float f) {
    union { float f; unsigned u; } a; a.f = f;
    unsigned r = a.u + 0x7FFFu + ((a.u >> 16) & 1u);   // RNE
    return (unsigned short)(r >> 16);
}

// ---- weight prep (R1-verbatim) ----
__global__ void prep_weights(const float* __restrict__ Wq,
                             const float* __restrict__ Wkv,
                             const float* __restrict__ Wp,
                             const float* __restrict__ bq,
                             const float* __restrict__ bkv,
                             u16* __restrict__ wt,
                             u16* __restrict__ wpt,
                             float* __restrict__ b_all)
{
    int idx = blockIdx.x * 256 + threadIdx.x;
    if (idx < 196608) {                       // 768*256
        int c = idx >> 8, k = idx & 255;
        float v = (c < 256) ? Wq[k * 256 + c] : Wkv[k * 512 + (c - 256)];
        wt[idx] = f2b(v);
    } else if (idx < 262144) {                // + 256*256
        int j = idx - 196608;
        int c = j >> 8, k = j & 255;
        wpt[j] = f2b(Wp[k * 256 + c]);
    } else if (idx < 262912) {                // + 768 biases
        int i = idx - 262144;
        b_all[i] = (i < 256) ? bq[i] : bkv[i - 256];
    }
}

// 8-wave variant of the R1-validated structure: 512 threads, wave w = head w.
// LDS (64 KiB):
//   region X [0,32768): xs[64][256] bf16 (512B rows, swz (row&7)<<4)
//                       -> V^T per-wave 4KB at w*4096 ([32 dh][64 tok], 128B rows, swz (dh&7)<<4)
//                       -> O_lds[64][256] (512B rows, swz (row&7)<<4)
//   region Y [32768,65536): per-wave 4KB chunk at 32768+w*4096:
//                       Q -> K -> P half0 -> P half1  ([64 tok][32 col], 64B rows,
//                       swz ((tok>>1)&3)<<4 — XOR-involution within row, 2-way-conflict-free)
// 2 blocks/CU (128KB LDS), 16 waves/CU = 4 waves/SIMD.
__global__ __launch_bounds__(512, 4)
void fused_win_attn(const float* __restrict__ x,
                    const float* __restrict__ mask,
                    const u16* __restrict__ wt,
                    const u16* __restrict__ wpt,
                    const float* __restrict__ b_all,
                    const float* __restrict__ bp,
                    float* __restrict__ out)
{
    __shared__ __align__(16) unsigned char smem[65536];
    const int b   = blockIdx.x;
    const int wdw = b & 255;                    // window index (batch-major layout)

    const int tid = threadIdx.x;
    const int w   = tid >> 6;                   // wave = head, 0..7
    const int l   = tid & 63;
    const int lr  = l & 15;
    const int lg  = l >> 4;
    const int chunk = 32768 + w * 4096;         // region Y: Q -> K -> P halves
    const int vtb   = w * 4096;                 // region X overlay: V^T
    const int hc    = w * 32;                   // head col base in Q/K/V space
    const float scale = 0.17677669529663687f;   // 1/sqrt(32)

    f32x4 zero = {0.f, 0.f, 0.f, 0.f};

    // ---------- Phase 1 (R1-verbatim formulas): stage x -> xs bf16 ----------
    {
        const float* xb = x + (size_t)b * 16384;
#pragma unroll
        for (int it = 0; it < 4; ++it) {
            int g   = it * 512 + tid;           // 8-float group id, 2048 total
            int row = g >> 5;
            int cg  = g & 31;
            const float4 f0 = *(const float4*)(xb + row * 256 + cg * 8);
            const float4 f1 = *(const float4*)(xb + row * 256 + cg * 8 + 4);
            u16v8 t;
            t[0] = f2b(f0.x); t[1] = f2b(f0.y); t[2] = f2b(f0.z); t[3] = f2b(f0.w);
            t[4] = f2b(f1.x); t[5] = f2b(f1.y); t[6] = f2b(f1.z); t[7] = f2b(f1.w);
            int off = row * 512 + ((cg * 16) ^ ((row & 7) << 4));
            *(u16x8*)(smem + off) = t;
        }
    }
    __syncthreads();   // #1

    // ---------- Phase 2: QKV for this head (hf token-halves; 2 tj col-tiles) ----------
    u32 pkK[2][2][2][2], pkV[2][2][2][2];   // [hf][t][tj][epair]
#pragma unroll
    for (int hf = 0; hf < 2; ++hf) {
        f32x4 qa[2][2], ka[2][2], va[2][2];
#pragma unroll
        for (int t = 0; t < 2; ++t)
#pragma unroll
            for (int tj = 0; tj < 2; ++tj) { qa[t][tj] = zero; ka[t][tj] = zero; va[t][tj] = zero; }
#pragma unroll
        for (int ks = 0; ks < 8; ++ks) {
            bf16v8 af[2];
#pragma unroll
            for (int t = 0; t < 2; ++t) {
                int row = hf * 32 + t * 16 + lr;
                af[t] = *(const bf16x8*)(smem + row * 512 + ((ks * 64 + lg * 16) ^ ((row & 7) << 4)));
            }
#pragma unroll
            for (int tj = 0; tj < 2; ++tj) {
                const u16* wp0 = wt + (size_t)(hc + tj * 16 + lr) * 256 + ks * 32 + lg * 8;
                bf16v8 bwq = *(const bf16x8*)(wp0);
                bf16v8 bwk = *(const bf16x8*)(wp0 + 256 * 256);
                bf16v8 bwv = *(const bf16x8*)(wp0 + 512 * 256);
#pragma unroll
                for (int t = 0; t < 2; ++t) {
                    qa[t][tj] = __builtin_amdgcn_mfma_f32_16x16x32_bf16(af[t], bwq, qa[t][tj], 0, 0, 0);
                    ka[t][tj] = __builtin_amdgcn_mfma_f32_16x16x32_bf16(af[t], bwk, ka[t][tj], 0, 0, 0);
                    va[t][tj] = __builtin_amdgcn_mfma_f32_16x16x32_bf16(af[t], bwv, va[t][tj], 0, 0, 0);
                }
            }
        }
        // stage Q half into chunk (cvtpk pair + lo/hi split, R5-validated pattern,
        // NEW 64B-row formula); park K,V (+bias) packed
#pragma unroll
        for (int tj = 0; tj < 2; ++tj) {
            float bqv = b_all[hc + tj * 16 + lr];
            float bkr = b_all[256 + hc + tj * 16 + lr];
            float bvr = b_all[512 + hc + tj * 16 + lr];
            int c2 = (tj * 16 + lr) * 2;
#pragma unroll
            for (int t = 0; t < 2; ++t) {
#pragma unroll
                for (int ep = 0; ep < 2; ++ep) {
                    u32 uq = cvtpk(qa[t][tj][2 * ep] + bqv, qa[t][tj][2 * ep + 1] + bqv);
                    int tok0 = hf * 32 + t * 16 + lg * 4 + ep * 2;
                    *(u16*)(smem + chunk + tok0 * 64 + (c2 ^ (((tok0 >> 1) & 3) << 4))) = (unsigned short)uq;
                    *(u16*)(smem + chunk + (tok0 + 1) * 64 + (c2 ^ ((((tok0 + 1) >> 1) & 3) << 4))) = (unsigned short)(uq >> 16);
                }
                pkK[hf][t][tj][0] = cvtpk(ka[t][tj][0] + bkr, ka[t][tj][1] + bkr);
                pkK[hf][t][tj][1] = cvtpk(ka[t][tj][2] + bkr, ka[t][tj][3] + bkr);
                pkV[hf][t][tj][0] = cvtpk(va[t][tj][0] + bvr, va[t][tj][1] + bvr);
                pkV[hf][t][tj][1] = cvtpk(va[t][tj][2] + bvr, va[t][tj][3] + bvr);
            }
        }
    }

    MEMFENCE();
    // read Q A-frags (4 q-tiles; dh=32 = one MFMA K)
    bf16v8 aq[4];
#pragma unroll
    for (int ti = 0; ti < 4; ++ti) {
        int row = ti * 16 + lr;
        aq[ti] = *(const bf16x8*)(smem + chunk + row * 64 + ((lg * 16) ^ (((row >> 1) & 3) << 4)));
    }
    MEMFENCE();

    // stage K into chunk (overwrite Q; lo/hi split pattern)
#pragma unroll
    for (int hf = 0; hf < 2; ++hf)
#pragma unroll
        for (int t = 0; t < 2; ++t)
#pragma unroll
            for (int tj = 0; tj < 2; ++tj) {
                int c2 = (tj * 16 + lr) * 2;
#pragma unroll
                for (int ep = 0; ep < 2; ++ep) {
                    u32 u = pkK[hf][t][tj][ep];
                    int tok0 = hf * 32 + t * 16 + lg * 4 + ep * 2;
                    *(u16*)(smem + chunk + tok0 * 64 + (c2 ^ (((tok0 >> 1) & 3) << 4))) = (unsigned short)u;
                    *(u16*)(smem + chunk + (tok0 + 1) * 64 + (c2 ^ ((((tok0 + 1) >> 1) & 3) << 4))) = (unsigned short)(u >> 16);
                }
            }
    MEMFENCE();

    // read K B-frags (4 k-token tiles)
    bf16v8 bk[4];
#pragma unroll
    for (int tj = 0; tj < 4; ++tj) {
        int n = tj * 16 + lr;
        bk[tj] = *(const bf16x8*)(smem + chunk + n * 64 + ((lg * 16) ^ (((n >> 1) & 3) << 4)));
    }

    // ---------- S = Q K^T + softmax (register-only; before the V^T barrier) ----------
    f32x4 sH[4][4];
#pragma unroll
    for (int ti = 0; ti < 4; ++ti)
#pragma unroll
        for (int tj = 0; tj < 4; ++tj)
            sH[ti][tj] = __builtin_amdgcn_mfma_f32_16x16x32_bf16(aq[ti], bk[tj], zero, 0, 0, 0);

    const float* mbase = mask + (size_t)wdw * 4096;
#pragma unroll
    for (int ti = 0; ti < 4; ++ti)
#pragma unroll
        for (int e = 0; e < 4; ++e) {
            int row = ti * 16 + lg * 4 + e;
#pragma unroll
            for (int tj = 0; tj < 4; ++tj)
                sH[ti][tj][e] = sH[ti][tj][e] * scale + mbase[row * 64 + tj * 16 + lr];
        }
    float inv[4][4];
#pragma unroll
    for (int ti = 0; ti < 4; ++ti)
#pragma unroll
        for (int e = 0; e < 4; ++e) {
            float v0 = sH[ti][0][e], v1 = sH[ti][1][e];
            float v2 = sH[ti][2][e], v3 = sH[ti][3][e];
            float m = fmaxf(fmaxf(v0, v1), fmaxf(v2, v3));
#pragma unroll
            for (int d = 1; d < 16; d <<= 1) m = fmaxf(m, __shfl_xor(m, d));
            v0 = __expf(v0 - m); v1 = __expf(v1 - m);
            v2 = __expf(v2 - m); v3 = __expf(v3 - m);
            float s = v0 + v1 + v2 + v3;
#pragma unroll
            for (int d = 1; d < 16; d <<= 1) s += __shfl_xor(s, d);
            inv[ti][e] = 1.0f / s;
            sH[ti][0][e] = v0; sH[ti][1][e] = v1;
            sH[ti][2][e] = v2; sH[ti][3][e] = v3;
        }
    // pack P to bf16 pairs (along e = consecutive q rows), freeing sH
    u32 pkP[4][4][2];
#pragma unroll
    for (int ti = 0; ti < 4; ++ti)
#pragma unroll
        for (int tj = 0; tj < 4; ++tj) {
            pkP[ti][tj][0] = cvtpk(sH[ti][tj][0], sH[ti][tj][1]);
            pkP[ti][tj][1] = cvtpk(sH[ti][tj][2], sH[ti][tj][3]);
        }

    __syncthreads();   // #2: all xs reads done -> region X becomes V^T tiles

    // stage V^T [32 dh][64 tok] (R1-verbatim vt formula, b64 packed)
#pragma unroll
    for (int hf = 0; hf < 2; ++hf)
#pragma unroll
        for (int t = 0; t < 2; ++t)
#pragma unroll
            for (int tj = 0; tj < 2; ++tj) {
                int dh = tj * 16 + lr;
                int tok0 = hf * 32 + t * 16 + lg * 4;
                u32x2 pv2; pv2[0] = pkV[hf][t][tj][0]; pv2[1] = pkV[hf][t][tj][1];
                *(u32x2*)(smem + vtb + dh * 128 + ((tok0 * 2) ^ ((dh & 7) << 4))) = pv2;
            }
    MEMFENCE();

    // ---------- PV in two k-halves (P half overwrites chunk; own-wave in-order) ----------
    f32x4 oH[4][2];
#pragma unroll
    for (int ti = 0; ti < 4; ++ti)
#pragma unroll
        for (int tjv = 0; tjv < 2; ++tjv) oH[ti][tjv] = zero;
#pragma unroll
    for (int kb = 0; kb < 2; ++kb) {
        // write P half kb: k-tiles tj = 2kb, 2kb+1 -> chunk [64 q][32 k]
#pragma unroll
        for (int ti = 0; ti < 4; ++ti)
#pragma unroll
            for (int tjh = 0; tjh < 2; ++tjh) {
                int c2 = (tjh * 16 + lr) * 2;
#pragma unroll
                for (int ep = 0; ep < 2; ++ep) {
                    u32 u = pkP[ti][2 * kb + tjh][ep];
                    int q0 = ti * 16 + lg * 4 + ep * 2;
                    *(u16*)(smem + chunk + q0 * 64 + (c2 ^ (((q0 >> 1) & 3) << 4))) = (unsigned short)u;
                    *(u16*)(smem + chunk + (q0 + 1) * 64 + (c2 ^ ((((q0 + 1) >> 1) & 3) << 4))) = (unsigned short)(u >> 16);
                }
            }
        MEMFENCE();
        // A-frags of P half; B-frags of V^T (R1-verbatim read formula)
        bf16v8 ap[4], bv[2];
#pragma unroll
        for (int ti = 0; ti < 4; ++ti) {
            int row = ti * 16 + lr;
            ap[ti] = *(const bf16x8*)(smem + chunk + row * 64 + ((lg * 16) ^ (((row >> 1) & 3) << 4)));
        }
#pragma unroll
        for (int tjv = 0; tjv < 2; ++tjv) {
            int dh = tjv * 16 + lr;
            bv[tjv] = *(const bf16x8*)(smem + vtb + dh * 128 + ((kb * 64 + lg * 16) ^ ((dh & 7) << 4)));
        }
#pragma unroll
        for (int ti = 0; ti < 4; ++ti)
#pragma unroll
            for (int tjv = 0; tjv < 2; ++tjv)
                oH[ti][tjv] = __builtin_amdgcn_mfma_f32_16x16x32_bf16(ap[ti], bv[tjv], oH[ti][tjv], 0, 0, 0);
        MEMFENCE();
    }
    // normalize O rows
#pragma unroll
    for (int ti = 0; ti < 4; ++ti)
#pragma unroll
        for (int tjv = 0; tjv < 2; ++tjv)
#pragma unroll
            for (int e = 0; e < 4; ++e)
                oH[ti][tjv][e] *= inv[ti][e];

    __syncthreads();   // #3: all PV done -> region X becomes O_lds

    // ---------- stage O -> O_lds[64][256] (R1-verbatim formula) ----------
#pragma unroll
    for (int ti = 0; ti < 4; ++ti)
#pragma unroll
        for (int tjv = 0; tjv < 2; ++tjv)
#pragma unroll
            for (int e = 0; e < 4; ++e) {
                int row = ti * 16 + lg * 4 + e;
                int cg  = hc + tjv * 16 + lr;
                *(u16*)(smem + row * 512 + ((cg * 2) ^ ((row & 7) << 4)))
                    = f2b(oH[ti][tjv][e]);
            }
    __syncthreads();   // #4

    // ---------- output projection (R1-verbatim, tj<2, cols hc..hc+32) ----------
    f32x4 pacc[4][2];
#pragma unroll
    for (int ti = 0; ti < 4; ++ti)
#pragma unroll
        for (int tj = 0; tj < 2; ++tj) pacc[ti][tj] = zero;
#pragma unroll
    for (int ks = 0; ks < 8; ++ks) {
        bf16v8 a_[4];
#pragma unroll
        for (int ti = 0; ti < 4; ++ti) {
            int row = ti * 16 + lr;
            a_[ti] = *(const bf16x8*)(smem + row * 512 + ((ks * 64 + lg * 16) ^ ((row & 7) << 4)));
        }
#pragma unroll
        for (int tj = 0; tj < 2; ++tj) {
            bf16v8 bw = *(const bf16x8*)(wpt + (size_t)(hc + tj * 16 + lr) * 256 + ks * 32 + lg * 8);
#pragma unroll
            for (int ti = 0; ti < 4; ++ti)
                pacc[ti][tj] = __builtin_amdgcn_mfma_f32_16x16x32_bf16(a_[ti], bw, pacc[ti][tj], 0, 0, 0);
        }
    }
    // epilogue (R1-verbatim tj-outer): + bp, store fp32
    float* ob = out + (size_t)b * 16384;
#pragma unroll
    for (int tj = 0; tj < 2; ++tj) {
        float bias = bp[hc + tj * 16 + lr];
#pragma unroll
        for (int ti = 0; ti < 4; ++ti)
#pragma unroll
            for (int e = 0; e < 4; ++e) {
                int row = ti * 16 + lg * 4 + e;
                ob[row * 256 + hc + tj * 16 + lr] = pacc[ti][tj][e] + bias;
            }
    }
}

extern "C" void kernel_launch(void* const* d_in, const int* in_sizes, int n_in,
                              void* d_out, int out_size, void* d_ws, size_t ws_size,
                              hipStream_t stream) {
    const float* x    = (const float*)d_in[0];
    const float* mask = (const float*)d_in[1];
    const float* Wq   = (const float*)d_in[2];
    const float* bq   = (const float*)d_in[3];
    const float* Wkv  = (const float*)d_in[4];
    const float* bkv  = (const float*)d_in[5];
    const float* Wp   = (const float*)d_in[6];
    const float* bp   = (const float*)d_in[7];
    float* out = (float*)d_out;

    u16*   wt    = (u16*)d_ws;                 // 768*256 bf16
    u16*   wpt   = wt + 768 * 256;             // 256*256 bf16
    float* b_all = (float*)(wpt + 256 * 256);  // 768 f32

    prep_weights<<<1027, 256, 0, stream>>>(Wq, Wkv, Wp, bq, bkv, wt, wpt, b_all);
    fused_win_attn<<<2048, 512, 0, stream>>>(x, mask, wt, wpt, b_all, bp, out);
}

// Round 8
// 278.774 us; speedup vs baseline: 1.6028x; 1.0672x over previous
//
#include <hip/hip_runtime.h>

// may_alias types for all LDS/global reinterpret accesses
typedef __bf16 bf16v8 __attribute__((ext_vector_type(8)));
typedef bf16v8 bf16x8 __attribute__((may_alias));
typedef unsigned int u32v2 __attribute__((ext_vector_type(2)));
typedef u32v2 u32x2 __attribute__((may_alias));
typedef unsigned short u16v8 __attribute__((ext_vector_type(8)));
typedef u16v8 u16x8 __attribute__((may_alias));
typedef unsigned short u16v;
typedef u16v u16 __attribute__((may_alias));
typedef _Float16 f16v4 __attribute__((ext_vector_type(4)));
typedef f16v4 f16x4 __attribute__((may_alias));
typedef _Float16 f16v;
typedef f16v f16s __attribute__((may_alias));
typedef float f32x4 __attribute__((ext_vector_type(4)));
typedef unsigned int u32;

#define MEMFENCE() asm volatile("" ::: "memory")

union B8 { u32 u[4]; bf16v8 v; };

__device__ __forceinline__ u32 cvtpk(float lo, float hi) {
    u32 r;
    asm("v_cvt_pk_bf16_f32 %0, %1, %2" : "=v"(r) : "v"(lo), "v"(hi));
    return r;
}

__device__ __forceinline__ unsigned short f2b(float f) {
    union { float f; unsigned u; } a; a.f = f;
    unsigned r = a.u + 0x7FFFu + ((a.u >> 16) & 1u);   // RNE
    return (unsigned short)(r >> 16);
}

// ---- weight prep (R1-verbatim) ----
__global__ void prep_weights(const float* __restrict__ Wq,
                             const float* __restrict__ Wkv,
                             const float* __restrict__ Wp,
                             const float* __restrict__ bq,
                             const float* __restrict__ bkv,
                             u16* __restrict__ wt,
                             u16* __restrict__ wpt,
                             float* __restrict__ b_all)
{
    int idx = blockIdx.x * 256 + threadIdx.x;
    if (idx < 196608) {                       // 768*256
        int c = idx >> 8, k = idx & 255;
        float v = (c < 256) ? Wq[k * 256 + c] : Wkv[k * 512 + (c - 256)];
        wt[idx] = f2b(v);
    } else if (idx < 262144) {                // + 256*256
        int j = idx - 196608;
        int c = j >> 8, k = j & 255;
        wpt[j] = f2b(Wp[k * 256 + c]);
    } else if (idx < 262912) {                // + 768 biases
        int i = idx - 262144;
        b_all[i] = (i < 256) ? bq[i] : bkv[i - 256];
    }
}

// R7-validated structure. Deltas: (1) mask staged ONCE per block into LDS f16 with
// column permutation col' = (k&15)*4 + (k>>4) so softmax reads ONE b64 per (ti,e)
// instead of 64 scalar global loads per lane; (2) s_setprio around MFMA clusters.
// LDS (72 KiB):
//   region X [0,32768): xs[64][256] -> V^T per-wave 4KB at w*4096 -> O_lds[64][256]
//   region Y [32768,65536): per-wave 4KB chunk: Q -> K -> P half0 -> P half1
//   mask     [65536,73728): mf16[64 q][64 k'] permuted cols, 128B rows, swz (q&7)<<4
__global__ __launch_bounds__(512, 4)
void fused_win_attn(const float* __restrict__ x,
                    const float* __restrict__ mask,
                    const u16* __restrict__ wt,
                    const u16* __restrict__ wpt,
                    const float* __restrict__ b_all,
                    const float* __restrict__ bp,
                    float* __restrict__ out)
{
    __shared__ __align__(16) unsigned char smem[73728];
    const int b   = blockIdx.x;
    const int wdw = b & 255;                    // window index (batch-major layout)

    const int tid = threadIdx.x;
    const int w   = tid >> 6;                   // wave = head, 0..7
    const int l   = tid & 63;
    const int lr  = l & 15;
    const int lg  = l >> 4;
    const int chunk = 32768 + w * 4096;         // region Y: Q -> K -> P halves
    const int vtb   = w * 4096;                 // region X overlay: V^T
    const int moff  = 65536;                    // mask f16
    const int hc    = w * 32;                   // head col base in Q/K/V space
    const float scale = 0.17677669529663687f;   // 1/sqrt(32)

    f32x4 zero = {0.f, 0.f, 0.f, 0.f};

    // ---------- Phase 1 (R7-verbatim): stage x -> xs bf16 ----------
    {
        const float* xb = x + (size_t)b * 16384;
#pragma unroll
        for (int it = 0; it < 4; ++it) {
            int g   = it * 512 + tid;           // 8-float group id, 2048 total
            int row = g >> 5;
            int cg  = g & 31;
            const float4 f0 = *(const float4*)(xb + row * 256 + cg * 8);
            const float4 f1 = *(const float4*)(xb + row * 256 + cg * 8 + 4);
            u16v8 t;
            t[0] = f2b(f0.x); t[1] = f2b(f0.y); t[2] = f2b(f0.z); t[3] = f2b(f0.w);
            t[4] = f2b(f1.x); t[5] = f2b(f1.y); t[6] = f2b(f1.z); t[7] = f2b(f1.w);
            int off = row * 512 + ((cg * 16) ^ ((row & 7) << 4));
            *(u16x8*)(smem + off) = t;
        }
    }
    // ---------- mask -> LDS f16, permuted cols (once per block, shared by 8 waves) ----------
    {
        const float* mb = mask + (size_t)wdw * 4096;
#pragma unroll
        for (int it = 0; it < 8; ++it) {
            int idx = it * 512 + tid;
            int q = idx >> 6, k = idx & 63;
            int colp = (k & 15) * 4 + (k >> 4);   // lane-contiguous tj packing
            *(f16s*)(smem + moff + q * 128 + ((colp * 2) ^ ((q & 7) << 4)))
                = (_Float16)mb[idx];
        }
    }
    __syncthreads();   // #1: xs + mask staged

    // ---------- Phase 2 (R7-verbatim): QKV for this head ----------
    u32 pkK[2][2][2][2], pkV[2][2][2][2];   // [hf][t][tj][epair]
#pragma unroll
    for (int hf = 0; hf < 2; ++hf) {
        f32x4 qa[2][2], ka[2][2], va[2][2];
#pragma unroll
        for (int t = 0; t < 2; ++t)
#pragma unroll
            for (int tj = 0; tj < 2; ++tj) { qa[t][tj] = zero; ka[t][tj] = zero; va[t][tj] = zero; }
#pragma unroll
        for (int ks = 0; ks < 8; ++ks) {
            bf16v8 af[2];
#pragma unroll
            for (int t = 0; t < 2; ++t) {
                int row = hf * 32 + t * 16 + lr;
                af[t] = *(const bf16x8*)(smem + row * 512 + ((ks * 64 + lg * 16) ^ ((row & 7) << 4)));
            }
            bf16v8 bwq[2], bwk[2], bwv[2];
#pragma unroll
            for (int tj = 0; tj < 2; ++tj) {
                const u16* wp0 = wt + (size_t)(hc + tj * 16 + lr) * 256 + ks * 32 + lg * 8;
                bwq[tj] = *(const bf16x8*)(wp0);
                bwk[tj] = *(const bf16x8*)(wp0 + 256 * 256);
                bwv[tj] = *(const bf16x8*)(wp0 + 512 * 256);
            }
            __builtin_amdgcn_s_setprio(1);
#pragma unroll
            for (int tj = 0; tj < 2; ++tj)
#pragma unroll
                for (int t = 0; t < 2; ++t) {
                    qa[t][tj] = __builtin_amdgcn_mfma_f32_16x16x32_bf16(af[t], bwq[tj], qa[t][tj], 0, 0, 0);
                    ka[t][tj] = __builtin_amdgcn_mfma_f32_16x16x32_bf16(af[t], bwk[tj], ka[t][tj], 0, 0, 0);
                    va[t][tj] = __builtin_amdgcn_mfma_f32_16x16x32_bf16(af[t], bwv[tj], va[t][tj], 0, 0, 0);
                }
            __builtin_amdgcn_s_setprio(0);
        }
        // stage Q half into chunk; park K,V (+bias) packed (R7-verbatim)
#pragma unroll
        for (int tj = 0; tj < 2; ++tj) {
            float bqv = b_all[hc + tj * 16 + lr];
            float bkr = b_all[256 + hc + tj * 16 + lr];
            float bvr = b_all[512 + hc + tj * 16 + lr];
            int c2 = (tj * 16 + lr) * 2;
#pragma unroll
            for (int t = 0; t < 2; ++t) {
#pragma unroll
                for (int ep = 0; ep < 2; ++ep) {
                    u32 uq = cvtpk(qa[t][tj][2 * ep] + bqv, qa[t][tj][2 * ep + 1] + bqv);
                    int tok0 = hf * 32 + t * 16 + lg * 4 + ep * 2;
                    *(u16*)(smem + chunk + tok0 * 64 + (c2 ^ (((tok0 >> 1) & 3) << 4))) = (unsigned short)uq;
                    *(u16*)(smem + chunk + (tok0 + 1) * 64 + (c2 ^ ((((tok0 + 1) >> 1) & 3) << 4))) = (unsigned short)(uq >> 16);
                }
                pkK[hf][t][tj][0] = cvtpk(ka[t][tj][0] + bkr, ka[t][tj][1] + bkr);
                pkK[hf][t][tj][1] = cvtpk(ka[t][tj][2] + bkr, ka[t][tj][3] + bkr);
                pkV[hf][t][tj][0] = cvtpk(va[t][tj][0] + bvr, va[t][tj][1] + bvr);
                pkV[hf][t][tj][1] = cvtpk(va[t][tj][2] + bvr, va[t][tj][3] + bvr);
            }
        }
    }

    MEMFENCE();
    // read Q A-frags (R7-verbatim)
    bf16v8 aq[4];
#pragma unroll
    for (int ti = 0; ti < 4; ++ti) {
        int row = ti * 16 + lr;
        aq[ti] = *(const bf16x8*)(smem + chunk + row * 64 + ((lg * 16) ^ (((row >> 1) & 3) << 4)));
    }
    MEMFENCE();

    // stage K into chunk (R7-verbatim)
#pragma unroll
    for (int hf = 0; hf < 2; ++hf)
#pragma unroll
        for (int t = 0; t < 2; ++t)
#pragma unroll
            for (int tj = 0; tj < 2; ++tj) {
                int c2 = (tj * 16 + lr) * 2;
#pragma unroll
                for (int ep = 0; ep < 2; ++ep) {
                    u32 u = pkK[hf][t][tj][ep];
                    int tok0 = hf * 32 + t * 16 + lg * 4 + ep * 2;
                    *(u16*)(smem + chunk + tok0 * 64 + (c2 ^ (((tok0 >> 1) & 3) << 4))) = (unsigned short)u;
                    *(u16*)(smem + chunk + (tok0 + 1) * 64 + (c2 ^ ((((tok0 + 1) >> 1) & 3) << 4))) = (unsigned short)(u >> 16);
                }
            }
    MEMFENCE();

    // read K B-frags (R7-verbatim)
    bf16v8 bk[4];
#pragma unroll
    for (int tj = 0; tj < 4; ++tj) {
        int n = tj * 16 + lr;
        bk[tj] = *(const bf16x8*)(smem + chunk + n * 64 + ((lg * 16) ^ (((n >> 1) & 3) << 4)));
    }

    // ---------- S = Q K^T + softmax (mask from LDS b64) ----------
    f32x4 sH[4][4];
    __builtin_amdgcn_s_setprio(1);
#pragma unroll
    for (int ti = 0; ti < 4; ++ti)
#pragma unroll
        for (int tj = 0; tj < 4; ++tj)
            sH[ti][tj] = __builtin_amdgcn_mfma_f32_16x16x32_bf16(aq[ti], bk[tj], zero, 0, 0, 0);
    __builtin_amdgcn_s_setprio(0);

#pragma unroll
    for (int ti = 0; ti < 4; ++ti)
#pragma unroll
        for (int e = 0; e < 4; ++e) {
            int row = ti * 16 + lg * 4 + e;
            f16v4 mv = *(const f16x4*)(smem + moff + row * 128 + ((lr * 8) ^ ((row & 7) << 4)));
#pragma unroll
            for (int tj = 0; tj < 4; ++tj)
                sH[ti][tj][e] = sH[ti][tj][e] * scale + (float)mv[tj];
        }
    float inv[4][4];
#pragma unroll
    for (int ti = 0; ti < 4; ++ti)
#pragma unroll
        for (int e = 0; e < 4; ++e) {
            float v0 = sH[ti][0][e], v1 = sH[ti][1][e];
            float v2 = sH[ti][2][e], v3 = sH[ti][3][e];
            float m = fmaxf(fmaxf(v0, v1), fmaxf(v2, v3));
#pragma unroll
            for (int d = 1; d < 16; d <<= 1) m = fmaxf(m, __shfl_xor(m, d));
            v0 = __expf(v0 - m); v1 = __expf(v1 - m);
            v2 = __expf(v2 - m); v3 = __expf(v3 - m);
            float s = v0 + v1 + v2 + v3;
#pragma unroll
            for (int d = 1; d < 16; d <<= 1) s += __shfl_xor(s, d);
            inv[ti][e] = 1.0f / s;
            sH[ti][0][e] = v0; sH[ti][1][e] = v1;
            sH[ti][2][e] = v2; sH[ti][3][e] = v3;
        }
    // pack P to bf16 pairs (R7-verbatim)
    u32 pkP[4][4][2];
#pragma unroll
    for (int ti = 0; ti < 4; ++ti)
#pragma unroll
        for (int tj = 0; tj < 4; ++tj) {
            pkP[ti][tj][0] = cvtpk(sH[ti][tj][0], sH[ti][tj][1]);
            pkP[ti][tj][1] = cvtpk(sH[ti][tj][2], sH[ti][tj][3]);
        }

    __syncthreads();   // #2: all xs reads done -> region X becomes V^T tiles

    // stage V^T (R7-verbatim)
#pragma unroll
    for (int hf = 0; hf < 2; ++hf)
#pragma unroll
        for (int t = 0; t < 2; ++t)
#pragma unroll
            for (int tj = 0; tj < 2; ++tj) {
                int dh = tj * 16 + lr;
                int tok0 = hf * 32 + t * 16 + lg * 4;
                u32x2 pv2; pv2[0] = pkV[hf][t][tj][0]; pv2[1] = pkV[hf][t][tj][1];
                *(u32x2*)(smem + vtb + dh * 128 + ((tok0 * 2) ^ ((dh & 7) << 4))) = pv2;
            }
    MEMFENCE();

    // ---------- PV in two k-halves (R7-verbatim) ----------
    f32x4 oH[4][2];
#pragma unroll
    for (int ti = 0; ti < 4; ++ti)
#pragma unroll
        for (int tjv = 0; tjv < 2; ++tjv) oH[ti][tjv] = zero;
#pragma unroll
    for (int kb = 0; kb < 2; ++kb) {
#pragma unroll
        for (int ti = 0; ti < 4; ++ti)
#pragma unroll
            for (int tjh = 0; tjh < 2; ++tjh) {
                int c2 = (tjh * 16 + lr) * 2;
#pragma unroll
                for (int ep = 0; ep < 2; ++ep) {
                    u32 u = pkP[ti][2 * kb + tjh][ep];
                    int q0 = ti * 16 + lg * 4 + ep * 2;
                    *(u16*)(smem + chunk + q0 * 64 + (c2 ^ (((q0 >> 1) & 3) << 4))) = (unsigned short)u;
                    *(u16*)(smem + chunk + (q0 + 1) * 64 + (c2 ^ ((((q0 + 1) >> 1) & 3) << 4))) = (unsigned short)(u >> 16);
                }
            }
        MEMFENCE();
        bf16v8 ap[4], bv[2];
#pragma unroll
        for (int ti = 0; ti < 4; ++ti) {
            int row = ti * 16 + lr;
            ap[ti] = *(const bf16x8*)(smem + chunk + row * 64 + ((lg * 16) ^ (((row >> 1) & 3) << 4)));
        }
#pragma unroll
        for (int tjv = 0; tjv < 2; ++tjv) {
            int dh = tjv * 16 + lr;
            bv[tjv] = *(const bf16x8*)(smem + vtb + dh * 128 + ((kb * 64 + lg * 16) ^ ((dh & 7) << 4)));
        }
        __builtin_amdgcn_s_setprio(1);
#pragma unroll
        for (int ti = 0; ti < 4; ++ti)
#pragma unroll
            for (int tjv = 0; tjv < 2; ++tjv)
                oH[ti][tjv] = __builtin_amdgcn_mfma_f32_16x16x32_bf16(ap[ti], bv[tjv], oH[ti][tjv], 0, 0, 0);
        __builtin_amdgcn_s_setprio(0);
        MEMFENCE();
    }
    // normalize O rows
#pragma unroll
    for (int ti = 0; ti < 4; ++ti)
#pragma unroll
        for (int tjv = 0; tjv < 2; ++tjv)
#pragma unroll
            for (int e = 0; e < 4; ++e)
                oH[ti][tjv][e] *= inv[ti][e];

    __syncthreads();   // #3: all PV done -> region X becomes O_lds

    // ---------- stage O -> O_lds[64][256] (R7-verbatim) ----------
#pragma unroll
    for (int ti = 0; ti < 4; ++ti)
#pragma unroll
        for (int tjv = 0; tjv < 2; ++tjv)
#pragma unroll
            for (int e = 0; e < 4; ++e) {
                int row = ti * 16 + lg * 4 + e;
                int cg  = hc + tjv * 16 + lr;
                *(u16*)(smem + row * 512 + ((cg * 2) ^ ((row & 7) << 4)))
                    = f2b(oH[ti][tjv][e]);
            }
    __syncthreads();   // #4

    // ---------- output projection (R7-verbatim) ----------
    f32x4 pacc[4][2];
#pragma unroll
    for (int ti = 0; ti < 4; ++ti)
#pragma unroll
        for (int tj = 0; tj < 2; ++tj) pacc[ti][tj] = zero;
#pragma unroll
    for (int ks = 0; ks < 8; ++ks) {
        bf16v8 a_[4];
#pragma unroll
        for (int ti = 0; ti < 4; ++ti) {
            int row = ti * 16 + lr;
            a_[ti] = *(const bf16x8*)(smem + row * 512 + ((ks * 64 + lg * 16) ^ ((row & 7) << 4)));
        }
        bf16v8 bw[2];
#pragma unroll
        for (int tj = 0; tj < 2; ++tj)
            bw[tj] = *(const bf16x8*)(wpt + (size_t)(hc + tj * 16 + lr) * 256 + ks * 32 + lg * 8);
        __builtin_amdgcn_s_setprio(1);
#pragma unroll
        for (int tj = 0; tj < 2; ++tj)
#pragma unroll
            for (int ti = 0; ti < 4; ++ti)
                pacc[ti][tj] = __builtin_amdgcn_mfma_f32_16x16x32_bf16(a_[ti], bw[tj], pacc[ti][tj], 0, 0, 0);
        __builtin_amdgcn_s_setprio(0);
    }
    // epilogue (R7-verbatim): + bp, store fp32
    float* ob = out + (size_t)b * 16384;
#pragma unroll
    for (int tj = 0; tj < 2; ++tj) {
        float bias = bp[hc + tj * 16 + lr];
#pragma unroll
        for (int ti = 0; ti < 4; ++ti)
#pragma unroll
            for (int e = 0; e < 4; ++e) {
                int row = ti * 16 + lg * 4 + e;
                ob[row * 256 + hc + tj * 16 + lr] = pacc[ti][tj][e] + bias;
            }
    }
}

extern "C" void kernel_launch(void* const* d_in, const int* in_sizes, int n_in,
                              void* d_out, int out_size, void* d_ws, size_t ws_size,
                              hipStream_t stream) {
    const float* x    = (const float*)d_in[0];
    const float* mask = (const float*)d_in[1];
    const float* Wq   = (const float*)d_in[2];
    const float* bq   = (const float*)d_in[3];
    const float* Wkv  = (const float*)d_in[4];
    const float* bkv  = (const float*)d_in[5];
    const float* Wp   = (const float*)d_in[6];
    const float* bp   = (const float*)d_in[7];
    float* out = (float*)d_out;

    u16*   wt    = (u16*)d_ws;                 // 768*256 bf16
    u16*   wpt   = wt + 768 * 256;             // 256*256 bf16
    float* b_all = (float*)(wpt + 256 * 256);  // 768 f32

    prep_weights<<<1027, 256, 0, stream>>>(Wq, Wkv, Wp, bq, bkv, wt, wpt, b_all);
    fused_win_attn<<<2048, 512, 0, stream>>>(x, mask, wt, wpt, b_all, bp, out);
}